// Round 1
// baseline (129.961 us; speedup 1.0000x reference)
//
#include <hip/hip_runtime.h>
#include <math.h>

#define NQ 8
#define FDIM 2048
#define EPSV 1e-5f

__launch_bounds__(256, 1)
__global__ void qtb_kernel(const float* __restrict__ x,
                           const float* __restrict__ theta,
                           const float* __restrict__ phi,
                           const float* __restrict__ W1,
                           const float* __restrict__ b1,
                           const float* __restrict__ W2,
                           const float* __restrict__ b2,
                           const float* __restrict__ g1,
                           const float* __restrict__ be1,
                           const float* __restrict__ g2,
                           const float* __restrict__ be2,
                           float* __restrict__ out,
                           int ntok)
{
    // 136 KB static LDS (gfx950 has 160 KB/CU): W1 row-major, W2 row-major
    // (original layout -> both staging and hot-loop reads conflict-free), b1.
    __shared__ float sW1[FDIM * NQ];   // [k][j]  64 KB
    __shared__ float sW2[NQ * FDIM];   // [i][k]  64 KB
    __shared__ float sB1[FDIM];        //          8 KB

    const int tid = threadIdx.x;

    // ---- stage weights to LDS (coalesced float4, one-time) ----
    {
        const float4* gw1 = reinterpret_cast<const float4*>(W1);
        const float4* gw2 = reinterpret_cast<const float4*>(W2);
        float4* s1p = reinterpret_cast<float4*>(sW1);
        float4* s2p = reinterpret_cast<float4*>(sW2);
        for (int i = tid; i < FDIM * NQ / 4; i += 256) {
            s1p[i] = gw1[i];
            s2p[i] = gw2[i];
        }
        const float4* gb = reinterpret_cast<const float4*>(b1);
        float4* sbp = reinterpret_cast<float4*>(sB1);
        for (int i = tid; i < FDIM / 4; i += 256) sbp[i] = gb[i];
    }
    __syncthreads();

    const int token = blockIdx.x * blockDim.x + tid;
    if (token >= ntok) return;

    // ---- load token ----
    const float4 xa = reinterpret_cast<const float4*>(x + (size_t)token * NQ)[0];
    const float4 xb = reinterpret_cast<const float4*>(x + (size_t)token * NQ)[1];
    float xv[8] = {xa.x, xa.y, xa.z, xa.w, xb.x, xb.y, xb.z, xb.w};

    // ---- attention: closed form of the 8-qubit CNOT-ring circuit ----
    // c_j = cos(x_j + theta_j); attn_0 = prod_{j=1..7} c_j; attn_i = prod_{j<=i} c_j
    float c[8];
#pragma unroll
    for (int j = 0; j < 8; ++j) c[j] = cosf(xv[j] + theta[j]);

    float attn[8];
    attn[0] = ((c[1]*c[2])*(c[3]*c[4]))*((c[5]*c[6])*c[7]);
    {
        float p = c[0];
#pragma unroll
        for (int j = 1; j < 8; ++j) { p *= c[j]; attn[j] = p; }
    }

    // ---- layernorm1(x + attn) ----
    float s[8];
#pragma unroll
    for (int j = 0; j < 8; ++j) s[j] = xv[j] + attn[j];
    float mean = 0.f;
#pragma unroll
    for (int j = 0; j < 8; ++j) mean += s[j];
    mean *= 0.125f;
    float var = 0.f;
#pragma unroll
    for (int j = 0; j < 8; ++j) { float d = s[j] - mean; var = fmaf(d, d, var); }
    var *= 0.125f;
    float rs = rsqrtf(var + EPSV);
    float h[8];
#pragma unroll
    for (int j = 0; j < 8; ++j) h[j] = (s[j] - mean) * rs * g1[j] + be1[j];

    // ---- ffn_quantum closed form: z_j = cos(phi_j) * cos(h_j) ----
    float zv[8];
#pragma unroll
    for (int j = 0; j < 8; ++j) zv[j] = cosf(phi[j]) * cosf(h[j]);

    // ---- FFN: relu(z @ W1^T + b1) @ W2^T  (2048x16 FMA per token) ----
    float acc[8] = {0.f,0.f,0.f,0.f,0.f,0.f,0.f,0.f};

#pragma unroll 2
    for (int k = 0; k < FDIM; k += 4) {
        const float4 bv = *reinterpret_cast<const float4*>(&sB1[k]);
        const float barr[4] = {bv.x, bv.y, bv.z, bv.w};
        float t[4];
#pragma unroll
        for (int m = 0; m < 4; ++m) {
            const float4 a = *reinterpret_cast<const float4*>(&sW1[(k + m) * NQ]);
            const float4 b = *reinterpret_cast<const float4*>(&sW1[(k + m) * NQ + 4]);
            float u = barr[m];
            u = fmaf(a.x, zv[0], u);
            u = fmaf(a.y, zv[1], u);
            u = fmaf(a.z, zv[2], u);
            u = fmaf(a.w, zv[3], u);
            u = fmaf(b.x, zv[4], u);
            u = fmaf(b.y, zv[5], u);
            u = fmaf(b.z, zv[6], u);
            u = fmaf(b.w, zv[7], u);
            t[m] = fmaxf(u, 0.f);
        }
#pragma unroll
        for (int i = 0; i < 8; ++i) {
            const float4 w = *reinterpret_cast<const float4*>(&sW2[i * FDIM + k]);
            float a2 = acc[i];
            a2 = fmaf(t[0], w.x, a2);
            a2 = fmaf(t[1], w.y, a2);
            a2 = fmaf(t[2], w.z, a2);
            a2 = fmaf(t[3], w.w, a2);
            acc[i] = a2;
        }
    }

    // ---- layernorm2(h + f) ----
    float y[8];
#pragma unroll
    for (int j = 0; j < 8; ++j) y[j] = h[j] + acc[j] + b2[j];
    float mean2 = 0.f;
#pragma unroll
    for (int j = 0; j < 8; ++j) mean2 += y[j];
    mean2 *= 0.125f;
    float var2 = 0.f;
#pragma unroll
    for (int j = 0; j < 8; ++j) { float d = y[j] - mean2; var2 = fmaf(d, d, var2); }
    var2 *= 0.125f;
    float rs2 = rsqrtf(var2 + EPSV);

    float o[8];
#pragma unroll
    for (int j = 0; j < 8; ++j) o[j] = (y[j] - mean2) * rs2 * g2[j] + be2[j];

    float4* op = reinterpret_cast<float4*>(out + (size_t)token * NQ);
    op[0] = make_float4(o[0], o[1], o[2], o[3]);
    op[1] = make_float4(o[4], o[5], o[6], o[7]);
}

extern "C" void kernel_launch(void* const* d_in, const int* in_sizes, int n_in,
                              void* d_out, int out_size, void* d_ws, size_t ws_size,
                              hipStream_t stream) {
    const float* x     = (const float*)d_in[0];
    const float* theta = (const float*)d_in[1];
    const float* phi   = (const float*)d_in[2];
    const float* W1    = (const float*)d_in[3];
    const float* b1    = (const float*)d_in[4];
    const float* W2    = (const float*)d_in[5];
    const float* b2    = (const float*)d_in[6];
    const float* g1    = (const float*)d_in[7];
    const float* be1   = (const float*)d_in[8];
    const float* g2    = (const float*)d_in[9];
    const float* be2   = (const float*)d_in[10];
    float* out = (float*)d_out;

    const int ntok = in_sizes[0] / NQ;           // 65536
    const int grid = (ntok + 255) / 256;         // 256 blocks -> 1/CU

    qtb_kernel<<<grid, 256, 0, stream>>>(x, theta, phi, W1, b1, W2, b2,
                                         g1, be1, g2, be2, out, ntok);
}